// Round 11
// baseline (674.934 us; speedup 1.0000x reference)
//
#include <hip/hip_runtime.h>
#include <math.h>

#define NNODES 50000
#define NEDGES 800000
#define BN_EPS 1e-5f
#define DEGC 128   // LDS-cached in-edges per node; fallback path beyond
#define NB 391     // buckets (128 nodes each; last has 80)
#define NPB 128
#define SCG 128    // scatter blocks (chunked)

typedef unsigned int uint;
typedef unsigned short ushort;

// fp32 -> bf16 (RNE)
static __device__ __forceinline__ ushort f2bf(float f) {
    uint u = __float_as_uint(f);
    return (ushort)((u + 0x7fffu + ((u >> 16) & 1u)) >> 16);
}
// 2 packed bf16 -> 2 fp32 (elem0 = low 16 bits)
static __device__ __forceinline__ float2 bf2f(uint v) {
    float2 r;
    r.x = __uint_as_float(v << 16);
    r.y = __uint_as_float(v & 0xffff0000u);
    return r;
}

// ================= CSR build via 2-level bucket sort =================
__global__ __launch_bounds__(256) void bucket_hist(const int* __restrict__ dst,
                                                   int* __restrict__ bcnt) {
    __shared__ int h[NB];
    for (int i = threadIdx.x; i < NB; i += 256) h[i] = 0;
    __syncthreads();
    for (int e = blockIdx.x * 256 + threadIdx.x; e < NEDGES; e += gridDim.x * 256)
        atomicAdd(&h[dst[e] >> 7], 1);
    __syncthreads();
    for (int i = threadIdx.x; i < NB; i += 256)
        if (h[i]) atomicAdd(&bcnt[i], h[i]);
}

__global__ void bucket_scan(const int* __restrict__ bcnt, int* __restrict__ eoff,
                            int* __restrict__ boff, int* __restrict__ ecur,
                            int* __restrict__ off) {
    __shared__ int w1[8], w2[8];
    int t = threadIdx.x, lane = t & 63, wv = t >> 6;  // 512 threads, 8 waves
    int v = (t < NB) ? bcnt[t] : 0;
    int nib = 0;
    if (t < NB) nib = (t == NB - 1) ? (NNODES - (NB - 1) * NPB) : NPB;
    int x1 = v, x2 = v + nib;
#pragma unroll
    for (int s = 1; s < 64; s <<= 1) {
        int t1 = __shfl_up(x1, s), t2 = __shfl_up(x2, s);
        if (lane >= s) { x1 += t1; x2 += t2; }
    }
    if (lane == 63) { w1[wv] = x1; w2[wv] = x2; }
    __syncthreads();
    if (wv == 0) {
        int a = (lane < 8) ? w1[lane] : 0, b = (lane < 8) ? w2[lane] : 0;
#pragma unroll
        for (int s = 1; s < 8; s <<= 1) {
            int ta = __shfl_up(a, s), tb = __shfl_up(b, s);
            if (lane >= s) { a += ta; b += tb; }
        }
        if (lane < 8) { w1[lane] = a; w2[lane] = b; }
    }
    __syncthreads();
    int p1 = (wv > 0) ? w1[wv - 1] : 0, p2 = (wv > 0) ? w2[wv - 1] : 0;
    x1 += p1; x2 += p2;
    if (t < NB) { eoff[t] = x1 - v; boff[t] = x2 - (v + nib); ecur[t] = 0; }
    if (t == NB - 1) { eoff[NB] = x1; boff[NB] = x2; off[NNODES] = x2; }
}

// block-aggregated scatter: per-block LDS hist -> one range-reservation atomic
// per (bucket, block) -> ticketed placement into contiguous runs.
__global__ __launch_bounds__(256) void bucket_scatter(const int* __restrict__ src,
                                                      const int* __restrict__ dst,
                                                      const int* __restrict__ eoff,
                                                      int* __restrict__ ecur,
                                                      uint* __restrict__ ebuf) {
    __shared__ int lh[NB];    // local hist -> global base
    __shared__ int lcur[NB];  // local ticket
    const int CH = (NEDGES + SCG - 1) / SCG;
    int c0 = blockIdx.x * CH;
    int c1 = min(c0 + CH, NEDGES);
    int t = threadIdx.x;
    for (int i = t; i < NB; i += 256) { lh[i] = 0; lcur[i] = 0; }
    __syncthreads();
    for (int e = c0 + t; e < c1; e += 256) atomicAdd(&lh[dst[e] >> 7], 1);
    __syncthreads();
    for (int i = t; i < NB; i += 256) {
        int c = lh[i];
        lh[i] = c ? (eoff[i] + atomicAdd(&ecur[i], c)) : 0;
    }
    __syncthreads();
    for (int e = c0 + t; e < c1; e += 256) {
        int d = dst[e];
        int bk = d >> 7;
        int p = lh[bk] + atomicAdd(&lcur[bk], 1);
        ebuf[p] = ((uint)(d & 127) << 16) | (uint)src[e];
    }
}

__global__ __launch_bounds__(256) void bucket_place(const uint* __restrict__ ebuf,
                                                    const int* __restrict__ eoff,
                                                    const int* __restrict__ boff,
                                                    int* __restrict__ off,
                                                    int* __restrict__ ssorted) {
    __shared__ int cnt[NPB];  // counts, then exclusive offsets
    __shared__ int cur[NPB];
    __shared__ int wtot[2];
    int b = blockIdx.x;
    int nib = (b == NB - 1) ? (NNODES - (NB - 1) * NPB) : NPB;
    int t = threadIdx.x;
    for (int i = t; i < NPB; i += 256) { cnt[i] = 0; cur[i] = 0; }
    __syncthreads();
    int e0 = eoff[b], e1 = eoff[b + 1];
    for (int i = e0 + t; i < e1; i += 256) atomicAdd(&cnt[ebuf[i] >> 16], 1);
    __syncthreads();
    int lane = t & 63, wv = t >> 6;
    int deg = (t < nib) ? cnt[t] + 1 : 0;  // +1 self-loop for real nodes
    int x = deg;
#pragma unroll
    for (int s = 1; s < 64; s <<= 1) {
        int tv = __shfl_up(x, s);
        if (lane >= s) x += tv;
    }
    if (lane == 63 && wv < 2) wtot[wv] = x;
    __syncthreads();
    int excl = x - deg + ((wv == 1) ? wtot[0] : 0);
    if (t < nib) {
        int base = boff[b] + excl;
        off[b * NPB + t] = base;
        cnt[t] = excl;                          // reuse as local offset
        ssorted[base + deg - 1] = b * NPB + t;  // self-loop in last slot
    }
    __syncthreads();
    int bb = boff[b];
    for (int i = e0 + t; i < e1; i += 256) {
        uint v = ebuf[i];
        int ld = v >> 16;
        int pos = bb + cnt[ld] + atomicAdd(&cur[ld], 1);
        ssorted[pos] = (int)(v & 0xffffu);
    }
}

// ===== dense matmul: O = (AFF? X*sc+sh : X) @ W (+bias), fused attn scores =====
// 64 x BN block tile, thread tile 4 x TN (TN=BN/16), register double-buffered
// K-tiles. AH=4 (BN=64): each head's 32 cols live in 8 lanes -> xor 1,2,4
// reduce, direct store. AH=1 (F=32): 16-lane row reduce, direct store.
template <int BN, bool WF32, bool WBF, bool AFF, bool BIAS, int AH>
__global__ __launch_bounds__(256) void matmul_rt(const float* __restrict__ X,
                                                 const float* __restrict__ W,
                                                 const float* __restrict__ scale,
                                                 const float* __restrict__ shift,
                                                 const float* __restrict__ bias,
                                                 const float* __restrict__ av_s,
                                                 const float* __restrict__ av_d,
                                                 float* __restrict__ Of,
                                                 ushort* __restrict__ Obf,
                                                 float* __restrict__ es,
                                                 float* __restrict__ ed,
                                                 int N, int K, int F) {
    constexpr int TN = BN / 16;
    constexpr int NXL = 4;              // 64*16/256 loads per thread (sX)
    constexpr int NWL = 16 * BN / 256;  // sW loads per thread
    __shared__ float sX[16][64 + 4];
    __shared__ float sW[16][BN + 4];
    int tid = threadIdx.x;
    int rowBase = blockIdx.x * 64, colBase = blockIdx.y * BN;
    int tr = (tid >> 4) * 4, tc = (tid & 15) * TN;
    float acc[4][TN];
#pragma unroll
    for (int x = 0; x < 4; ++x)
#pragma unroll
        for (int y = 0; y < TN; ++y) acc[x][y] = 0.f;

    float rx[NXL], rw[NWL];
    auto loadX = [&](int k0) {
#pragma unroll
        for (int j = 0; j < NXL; ++j) {
            int i = tid + j * 256;
            int r = i >> 4, k = i & 15;
            int gr = rowBase + r;
            float v = 0.f;
            if (gr < N) {
                v = X[(size_t)gr * K + k0 + k];
                if constexpr (AFF) v = fmaf(v, scale[k0 + k], shift[k0 + k]);
            }
            rx[j] = v;
        }
    };
    auto loadW = [&](int k0) {
#pragma unroll
        for (int j = 0; j < NWL; ++j) {
            int i = tid + j * 256;
            rw[j] = W[(size_t)(k0 + i / BN) * F + colBase + i % BN];
        }
    };

    loadX(0);
    loadW(0);
    const int T = K / 16;
    for (int t = 0; t < T; ++t) {
#pragma unroll
        for (int j = 0; j < NXL; ++j) {
            int i = tid + j * 256;
            sX[i & 15][i >> 4] = rx[j];
        }
#pragma unroll
        for (int j = 0; j < NWL; ++j) {
            int i = tid + j * 256;
            sW[i / BN][i % BN] = rw[j];
        }
        __syncthreads();
        if (t + 1 < T) {  // issue next tile's loads; they fly during compute
            loadX((t + 1) * 16);
            loadW((t + 1) * 16);
        }
#pragma unroll
        for (int k = 0; k < 16; ++k) {
            float4 av = *(const float4*)&sX[k][tr];
            float a[4] = {av.x, av.y, av.z, av.w};
            float b[TN];
            if constexpr (TN == 4) {
                float4 bv = *(const float4*)&sW[k][tc];
                b[0] = bv.x; b[1] = bv.y; b[2] = bv.z; b[3] = bv.w;
            } else {
                float2 bv = *(const float2*)&sW[k][tc];
                b[0] = bv.x; b[1] = bv.y;
            }
#pragma unroll
            for (int x = 0; x < 4; ++x)
#pragma unroll
                for (int y = 0; y < TN; ++y) acc[x][y] += a[x] * b[y];
        }
        __syncthreads();
    }

    float asv[TN], adv[TN];
    if constexpr (AH > 0) {
#pragma unroll
        for (int y = 0; y < TN; ++y) {
            asv[y] = av_s[colBase + tc + y];
            adv[y] = av_d[colBase + tc + y];
        }
    }

#pragma unroll
    for (int x = 0; x < 4; ++x) {
        int gr = rowBase + tr + x;
        float o[TN];
#pragma unroll
        for (int y = 0; y < TN; ++y) {
            o[y] = acc[x][y];
            if constexpr (BIAS) o[y] += bias[colBase + tc + y];
        }
        if (gr < N) {
            if constexpr (WF32) {
#pragma unroll
                for (int y = 0; y < TN; ++y) Of[(size_t)gr * F + colBase + tc + y] = o[y];
            }
            if constexpr (WBF) {
#pragma unroll
                for (int y = 0; y < TN; y += 2) {
                    uint pk = (uint)f2bf(o[y]) | ((uint)f2bf(o[y + 1]) << 16);
                    *(uint*)(Obf + (size_t)gr * F + colBase + tc + y) = pk;
                }
            }
        }
        if constexpr (AH > 0) {
            float ps = 0.f, pd = 0.f;
#pragma unroll
            for (int y = 0; y < TN; ++y) { ps += o[y] * asv[y]; pd += o[y] * adv[y]; }
            if constexpr (AH == 4) {
                // TN==4: thread's 4 cols in one 32-col head; 8 lanes cover it.
#pragma unroll
                for (int s = 1; s < 8; s <<= 1) { ps += __shfl_xor(ps, s); pd += __shfl_xor(pd, s); }
                if ((tid & 7) == 0 && gr < N) {
                    int hd = (colBase >> 5) + (tc >> 5);
                    es[(size_t)gr * 4 + hd] = ps;
                    ed[(size_t)gr * 4 + hd] = pd;
                }
            } else {
                // 16 lanes share the row, single head, single col-block
#pragma unroll
                for (int s = 1; s < 16; s <<= 1) { ps += __shfl_xor(ps, s); pd += __shfl_xor(pd, s); }
                if ((tid & 15) == 0 && gr < N) { es[gr] = ps; ed[gr] = pd; }
            }
        }
    }
}

// fold a_src/a_dst through W5: atl[0..31]=W5@as5, atl[32..63]=W5@ad5
__global__ void atilde_k(const float* __restrict__ W5, const float* __restrict__ as5,
                         const float* __restrict__ ad5, float* __restrict__ atl) {
    int t = threadIdx.x;
    if (t >= 64) return;
    int k = t & 31;
    const float* a = (t < 32) ? as5 : ad5;
    float s = 0.f;
    for (int f = 0; f < 128; ++f) s += W5[k * 128 + f] * a[f];
    atl[t] = s;
}

// ====== XCD-sliced gather softmax-aggregate, F=128, HH=4, h in bf16 ======
// 1-D grid of N blocks; slice (== head) = (bid&7)>>1 pins each 32-feature
// slice (3.2 MB bf16) to one XCD pair's L2. Wave = one node's slice; 16
// lanes/neighbor (64B line), 4 neighbors in flight, xor16/32 reduce.
__global__ __launch_bounds__(256) void node_agg_bf4(const int* __restrict__ off,
                                                    const int* __restrict__ ssorted,
                                                    const ushort* __restrict__ Hb,
                                                    const float* __restrict__ es,
                                                    const float* __restrict__ ed,
                                                    const float* __restrict__ bias,
                                                    float* __restrict__ outp, int relu) {
    __shared__ float lds_ex[4][DEGC];
    __shared__ int lds_s[4][DEGC];
    int bid = blockIdx.x;
    int sl = (bid & 7) >> 1;                  // head/slice 0..3
    int grp = ((bid >> 3) << 1) + (bid & 1);  // node group 0..N/4
    int wib = threadIdx.x >> 6;
    int lane = threadIdx.x & 63;
    int d = grp * 4 + wib;
    int beg = off[d], end = off[d + 1];
    int m = end - beg;  // >= 1

    float edv = ed[(size_t)d * 4 + sl];
    float denp = 0.f;
    for (int base = 0; base < m; base += 64) {
        int i = base + lane;
        if (i < m) {
            int s = ssorted[beg + i];
            if (i < DEGC) lds_s[wib][i] = s;
            float a = es[(size_t)s * 4 + sl] + edv;
            a = a > 0.f ? a : 0.2f * a;
            float ex = __expf(a);
            denp += ex;
            if (i < DEGC) lds_ex[wib][i] = ex;
        }
    }
#pragma unroll
    for (int sft = 1; sft < 64; sft <<= 1) denp += __shfl_xor(denp, sft);

    __syncthreads();

    const uint* Hu = (const uint*)Hb;
    int sub = lane >> 4, fu = lane & 15;  // neighbor sub-group, uint-in-slice
    int ub = sl * 16 + fu;                // uint index within the 64-uint row
    float inv = 1.f / denp;
    float acc0 = 0.f, acc1 = 0.f;
    int mu = m < DEGC ? m : DEGC;
    int i = sub;
    for (; i + 4 < mu; i += 8) {  // 2-deep MLP per sub-group
        int s0 = lds_s[wib][i], s1 = lds_s[wib][i + 4];
        float w0 = lds_ex[wib][i] * inv, w1 = lds_ex[wib][i + 4] * inv;
        float2 f0 = bf2f(Hu[(size_t)s0 * 64 + ub]);
        float2 f1 = bf2f(Hu[(size_t)s1 * 64 + ub]);
        acc0 += w0 * f0.x + w1 * f1.x;
        acc1 += w0 * f0.y + w1 * f1.y;
    }
    for (; i < mu; i += 4) {
        int s = lds_s[wib][i];
        float w = lds_ex[wib][i] * inv;
        float2 f = bf2f(Hu[(size_t)s * 64 + ub]);
        acc0 += w * f.x;
        acc1 += w * f.y;
    }
    for (; i < m; i += 4) {  // rare high-degree fallback
        int s = ssorted[beg + i];
        float a = es[(size_t)s * 4 + sl] + edv;
        a = a > 0.f ? a : 0.2f * a;
        float w = __expf(a) * inv;
        float2 f = bf2f(Hu[(size_t)s * 64 + ub]);
        acc0 += w * f.x;
        acc1 += w * f.y;
    }
    acc0 += __shfl_xor(acc0, 16); acc0 += __shfl_xor(acc0, 32);
    acc1 += __shfl_xor(acc1, 16); acc1 += __shfl_xor(acc1, 32);
    if (sub == 0) {
        int f0 = sl * 32 + 2 * fu;
        float v0 = acc0 + bias[f0];
        float v1 = acc1 + bias[f0 + 1];
        if (relu) { v0 = fmaxf(v0, 0.f); v1 = fmaxf(v1, 0.f); }
        *(float2*)(outp + (size_t)d * 128 + f0) = make_float2(v0, v1);
    }
}

// ====== XCD-sliced gather softmax-aggregate, F=32, HH=1, h in fp32 ======
// 1-D grid of N/2 blocks; slice = (bid&7)>>2 pins each 16-feature slice
// (3.2 MB fp32) to one XCD quad. Phase-1 softmax duplicated 2x (cheap).
__global__ __launch_bounds__(256) void node_agg_f32(const int* __restrict__ off,
                                                    const int* __restrict__ ssorted,
                                                    const float* __restrict__ Hb,
                                                    const float* __restrict__ es,
                                                    const float* __restrict__ ed,
                                                    const float* __restrict__ bias,
                                                    float* __restrict__ outp, int relu) {
    __shared__ float lds_ex[4][DEGC];
    __shared__ int lds_s[4][DEGC];
    int bid = blockIdx.x;
    int sl = (bid & 7) >> 2;                  // slice 0..1
    int grp = ((bid >> 3) << 2) + (bid & 3);  // node group 0..N/4
    int wib = threadIdx.x >> 6;
    int lane = threadIdx.x & 63;
    int d = grp * 4 + wib;
    int beg = off[d], end = off[d + 1];
    int m = end - beg;

    float edv = ed[d];
    float denp = 0.f;
    for (int base = 0; base < m; base += 64) {
        int i = base + lane;
        if (i < m) {
            int s = ssorted[beg + i];
            if (i < DEGC) lds_s[wib][i] = s;
            float a = es[s] + edv;
            a = a > 0.f ? a : 0.2f * a;
            float ex = __expf(a);
            denp += ex;
            if (i < DEGC) lds_ex[wib][i] = ex;
        }
    }
#pragma unroll
    for (int sft = 1; sft < 64; sft <<= 1) denp += __shfl_xor(denp, sft);

    __syncthreads();

    int sub = lane >> 4, fu = lane & 15;
    int f = sl * 16 + fu;
    float inv = 1.f / denp;
    float acc = 0.f;
    int mu = m < DEGC ? m : DEGC;
    int i = sub;
    for (; i + 4 < mu; i += 8) {  // 2-deep MLP per sub-group
        int s0 = lds_s[wib][i], s1 = lds_s[wib][i + 4];
        float w0 = lds_ex[wib][i] * inv, w1 = lds_ex[wib][i + 4] * inv;
        acc += w0 * Hb[(size_t)s0 * 32 + f] + w1 * Hb[(size_t)s1 * 32 + f];
    }
    for (; i < mu; i += 4) {
        int s = lds_s[wib][i];
        acc += lds_ex[wib][i] * inv * Hb[(size_t)s * 32 + f];
    }
    for (; i < m; i += 4) {
        int s = ssorted[beg + i];
        float a = es[s] + edv;
        a = a > 0.f ? a : 0.2f * a;
        acc += __expf(a) * inv * Hb[(size_t)s * 32 + f];
    }
    acc += __shfl_xor(acc, 16);
    acc += __shfl_xor(acc, 32);
    if (sub == 0) {
        float v = acc + bias[f];
        if (relu) v = fmaxf(v, 0.f);
        outp[(size_t)d * 32 + f] = v;
    }
}

// ================= batchnorm =================
template <int F>
__global__ __launch_bounds__(256) void bn_stats(const float* __restrict__ x,
                                                float* __restrict__ sums, int n) {
    constexpr int TPR = F / 4;
    constexpr int RPB = 256 / TPR;
    __shared__ float ls[2 * F];
    if (threadIdx.x < 2 * F) ls[threadIdx.x] = 0.f;
    int tf = threadIdx.x % TPR;
    int tr = threadIdx.x / TPR;
    float4 s = make_float4(0.f, 0.f, 0.f, 0.f), q = make_float4(0.f, 0.f, 0.f, 0.f);
    for (int r = blockIdx.x * RPB + tr; r < n; r += gridDim.x * RPB) {
        float4 v = *(const float4*)(x + (size_t)r * F + tf * 4);
        s.x += v.x; s.y += v.y; s.z += v.z; s.w += v.w;
        q.x += v.x * v.x; q.y += v.y * v.y; q.z += v.z * v.z; q.w += v.w * v.w;
    }
    __syncthreads();
    atomicAdd(&ls[tf * 4 + 0], s.x);
    atomicAdd(&ls[tf * 4 + 1], s.y);
    atomicAdd(&ls[tf * 4 + 2], s.z);
    atomicAdd(&ls[tf * 4 + 3], s.w);
    atomicAdd(&ls[F + tf * 4 + 0], q.x);
    atomicAdd(&ls[F + tf * 4 + 1], q.y);
    atomicAdd(&ls[F + tf * 4 + 2], q.z);
    atomicAdd(&ls[F + tf * 4 + 3], q.w);
    __syncthreads();
    if (threadIdx.x < 2 * F) atomicAdd(&sums[threadIdx.x], ls[threadIdx.x]);
}

// sums -> per-feature scale/shift (bn folded into next matmul's staging)
__global__ void bn_final(const float* __restrict__ sums, const float* __restrict__ g,
                         const float* __restrict__ be, float* __restrict__ sc,
                         float* __restrict__ sh, int F, float inv_n) {
    int f = threadIdx.x;
    if (f >= F) return;
    float mu = sums[f] * inv_n;
    float var = sums[F + f] * inv_n - mu * mu;
    float s = g[f] * rsqrtf(var + BN_EPS);
    sc[f] = s;
    sh[f] = fmaf(-mu, s, be[f]);
}

// bn + relu + fused GAT5 attn scores (one 32-lane group per row)
__global__ __launch_bounds__(256) void bn_relu_attn(const float* __restrict__ y,
                                                    const float* __restrict__ sums,
                                                    const float* __restrict__ g,
                                                    const float* __restrict__ be,
                                                    const float* __restrict__ atl,
                                                    float* __restrict__ o,
                                                    float* __restrict__ es,
                                                    float* __restrict__ ed) {
    int r = blockIdx.x * 8 + (threadIdx.x >> 5);
    int f = threadIdx.x & 31;
    float mu = sums[f] / (float)NNODES;
    float var = sums[32 + f] / (float)NNODES - mu * mu;
    float v = (y[(size_t)r * 32 + f] - mu) * rsqrtf(var + BN_EPS) * g[f] + be[f];
    v = fmaxf(v, 0.f);
    o[(size_t)r * 32 + f] = v;
    float ps = v * atl[f], pd = v * atl[32 + f];
#pragma unroll
    for (int s = 1; s < 32; s <<= 1) { ps += __shfl_xor(ps, s); pd += __shfl_xor(pd, s); }
    if (f == 0) { es[r] = ps; ed[r] = pd; }
}

extern "C" void kernel_launch(void* const* d_in, const int* in_sizes, int n_in, void* d_out,
                              int out_size, void* d_ws, size_t ws_size, hipStream_t stream) {
    const int N = NNODES, E = NEDGES;
    const float* x = (const float*)d_in[0];
    const int* ei = (const int*)d_in[1];
    const int* src = ei;
    const int* dst = ei + E;
    const float* W1 = (const float*)d_in[2];
    const float* as1 = (const float*)d_in[3];
    const float* ad1 = (const float*)d_in[4];
    const float* b1 = (const float*)d_in[5];
    const float* g1 = (const float*)d_in[6];
    const float* be1 = (const float*)d_in[7];
    const float* W2 = (const float*)d_in[8];
    const float* as2 = (const float*)d_in[9];
    const float* ad2 = (const float*)d_in[10];
    const float* b2 = (const float*)d_in[11];
    const float* g2 = (const float*)d_in[12];
    const float* be2 = (const float*)d_in[13];
    const float* W3 = (const float*)d_in[14];
    const float* as3 = (const float*)d_in[15];
    const float* ad3 = (const float*)d_in[16];
    const float* b3 = (const float*)d_in[17];
    const float* W4 = (const float*)d_in[18];
    const float* as4 = (const float*)d_in[19];
    const float* ad4 = (const float*)d_in[20];
    const float* b4 = (const float*)d_in[21];
    const float* g4 = (const float*)d_in[22];
    const float* be4 = (const float*)d_in[23];
    const float* W5 = (const float*)d_in[24];
    const float* as5 = (const float*)d_in[25];
    const float* ad5 = (const float*)d_in[26];
    const float* b5 = (const float*)d_in[27];
    float* out = (float*)d_out;

    // workspace layout (float-sized slots)
    float* ws = (float*)d_ws;
    float* bufAf = ws;                                      // N*128 fp32 (h for f32 layers)
    float* bufB = ws + (size_t)N * 128;                     // N*128 fp32 (activations)
    ushort* bufAbf = (ushort*)(ws + (size_t)2 * N * 128);   // N*128 bf16 (= N*64 floats)
    uint* ebuf = (uint*)bufAbf;                             // E uints, aliased (CSR build only)
    float* esA = ws + (size_t)2 * N * 128 + (size_t)N * 64; // N*4
    float* edA = esA + (size_t)N * 4;                       // N*4
    float* esB = edA + (size_t)N * 4;                       // N*4
    float* edB = esB + (size_t)N * 4;                       // N*4
    float* sums = edB + (size_t)N * 4;                      // 3*256
    float* zero32 = sums + 768;                             // 32
    int* bcnt = (int*)(zero32 + 32);                        // NB
    int* eoff = bcnt + NB;                                  // NB+1
    int* boff = eoff + NB + 1;                              // NB+1
    int* ecur = boff + NB + 1;                              // NB
    float* sc1 = (float*)(ecur + NB);                       // 128
    float* sh1 = sc1 + 128;
    float* sc2 = sh1 + 128;
    float* sh2 = sc2 + 128;
    float* atl = sh2 + 128;                                 // 64 (ãs | ãd)
    int* off = (int*)(atl + 64);                            // N+1
    int* ssorted = off + N + 1;                             // E+N

    const int TB = 256;
    const int gAggBf = N;      // sliced: 4 slices x N/4 groups
    const int gAggF32 = N / 2; // sliced: 2 slices x N/4 groups
    const dim3 mmG128((N + 63) / 64, 2);   // BN=64, two col-blocks
    const dim3 mmG32((N + 63) / 64, 1);    // BN=32, F=32
    const float inv_n = 1.f / (float)N;

    // zero sums(768) + zero32(32) + bcnt(NB)
    hipMemsetAsync(sums, 0, (768 + 32 + NB) * sizeof(float), stream);

    // ---- CSR-by-dst build (2-level bucket sort, block-aggregated scatter) ----
    bucket_hist<<<64, TB, 0, stream>>>(dst, bcnt);
    bucket_scan<<<1, 512, 0, stream>>>(bcnt, eoff, boff, ecur, off);
    bucket_scatter<<<SCG, TB, 0, stream>>>(src, dst, eoff, ecur, ebuf);
    bucket_place<<<NB, TB, 0, stream>>>(ebuf, eoff, boff, off, ssorted);
    atilde_k<<<1, 64, 0, stream>>>(W5, as5, ad5, atl);

    // ================= GAT1: 128 -> 4x32, relu, bn(fused fwd) =================
    matmul_rt<64, false, true, false, false, 4><<<mmG128, TB, 0, stream>>>(
        x, W1, nullptr, nullptr, nullptr, as1, ad1, nullptr, bufAbf, esA, edA, N, 128, 128);
    node_agg_bf4<<<gAggBf, TB, 0, stream>>>(off, ssorted, bufAbf, esA, edA, b1, bufB, 1);
    bn_stats<128><<<625, TB, 0, stream>>>(bufB, sums, N);
    bn_final<<<1, 128, 0, stream>>>(sums, g1, be1, sc1, sh1, 128, inv_n);

    // ================= GAT2: 128 -> 4x32, relu, bn(fused fwd) =================
    matmul_rt<64, false, true, true, false, 4><<<mmG128, TB, 0, stream>>>(
        bufB, W2, sc1, sh1, nullptr, as2, ad2, nullptr, bufAbf, esB, edB, N, 128, 128);
    node_agg_bf4<<<gAggBf, TB, 0, stream>>>(off, ssorted, bufAbf, esB, edB, b2, bufB, 1);
    bn_stats<128><<<625, TB, 0, stream>>>(bufB, sums + 256, N);
    bn_final<<<1, 128, 0, stream>>>(sums + 256, g2, be2, sc2, sh2, 128, inv_n);

    // ================= GAT3: 128 -> 32, relu (fp32 path, bn2 fused in) =================
    matmul_rt<32, true, false, true, false, 1><<<mmG32, TB, 0, stream>>>(
        bufB, W3, sc2, sh2, nullptr, as3, ad3, bufAf, nullptr, esA, edA, N, 128, 32);
    node_agg_f32<<<gAggF32, TB, 0, stream>>>(off, ssorted, bufAf, esA, edA, b3, bufB, 1);

    // ================= GAT4: 32 -> 32, relu, bn, relu =================
    matmul_rt<32, true, false, false, false, 1><<<mmG32, TB, 0, stream>>>(
        bufB, W4, nullptr, nullptr, nullptr, as4, ad4, bufAf, nullptr, esA, edA, N, 32, 32);
    node_agg_f32<<<gAggF32, TB, 0, stream>>>(off, ssorted, bufAf, esA, edA, b4, bufB, 1);
    bn_stats<32><<<625, TB, 0, stream>>>(bufB, sums + 512, N);
    bn_relu_attn<<<N / 8, TB, 0, stream>>>(bufB, sums + 512, g4, be4, atl, bufAf, esA, edA);

    // ================= GAT5: 32 -> 128 in r-space (exact fp32) =================
    node_agg_f32<<<gAggF32, TB, 0, stream>>>(off, ssorted, bufAf, esA, edA, zero32, bufB, 0);
    matmul_rt<64, true, false, false, true, 0><<<mmG128, TB, 0, stream>>>(
        bufB, W5, nullptr, nullptr, b5, nullptr, nullptr, out, nullptr, nullptr, nullptr,
        N, 32, 128);
}

// Round 12
// 579.503 us; speedup vs baseline: 1.1647x; 1.1647x over previous
//
#include <hip/hip_runtime.h>
#include <math.h>

#define NNODES 50000
#define NEDGES 800000
#define BN_EPS 1e-5f
#define DEGC 128   // LDS-cached in-edges per node; fallback path beyond
#define NB 391     // buckets (128 nodes each; last has 80)
#define NPB 128
#define SCG 128    // scatter blocks (chunked)

typedef unsigned int uint;
typedef unsigned short ushort;

// fp32 -> bf16 (RNE)
static __device__ __forceinline__ ushort f2bf(float f) {
    uint u = __float_as_uint(f);
    return (ushort)((u + 0x7fffu + ((u >> 16) & 1u)) >> 16);
}
// 2 packed bf16 -> 2 fp32 (elem0 = low 16 bits)
static __device__ __forceinline__ float2 bf2f(uint v) {
    float2 r;
    r.x = __uint_as_float(v << 16);
    r.y = __uint_as_float(v & 0xffff0000u);
    return r;
}

// ================= CSR build via 2-level bucket sort =================
__global__ __launch_bounds__(256) void bucket_hist(const int* __restrict__ dst,
                                                   int* __restrict__ bcnt) {
    __shared__ int h[NB];
    for (int i = threadIdx.x; i < NB; i += 256) h[i] = 0;
    __syncthreads();
    for (int e = blockIdx.x * 256 + threadIdx.x; e < NEDGES; e += gridDim.x * 256)
        atomicAdd(&h[dst[e] >> 7], 1);
    __syncthreads();
    for (int i = threadIdx.x; i < NB; i += 256)
        if (h[i]) atomicAdd(&bcnt[i], h[i]);
}

// scan over buckets (+ fused atilde: atl[0..31]=W5@as5, atl[32..63]=W5@ad5
// computed by otherwise-idle threads 448..511)
__global__ void bucket_scan(const int* __restrict__ bcnt, int* __restrict__ eoff,
                            int* __restrict__ boff, int* __restrict__ ecur,
                            int* __restrict__ off, const float* __restrict__ W5,
                            const float* __restrict__ as5, const float* __restrict__ ad5,
                            float* __restrict__ atl) {
    __shared__ int w1[8], w2[8];
    int t = threadIdx.x, lane = t & 63, wv = t >> 6;  // 512 threads, 8 waves
    int v = (t < NB) ? bcnt[t] : 0;
    int nib = 0;
    if (t < NB) nib = (t == NB - 1) ? (NNODES - (NB - 1) * NPB) : NPB;
    int x1 = v, x2 = v + nib;
#pragma unroll
    for (int s = 1; s < 64; s <<= 1) {
        int t1 = __shfl_up(x1, s), t2 = __shfl_up(x2, s);
        if (lane >= s) { x1 += t1; x2 += t2; }
    }
    if (lane == 63) { w1[wv] = x1; w2[wv] = x2; }
    __syncthreads();
    if (wv == 0) {
        int a = (lane < 8) ? w1[lane] : 0, b = (lane < 8) ? w2[lane] : 0;
#pragma unroll
        for (int s = 1; s < 8; s <<= 1) {
            int ta = __shfl_up(a, s), tb = __shfl_up(b, s);
            if (lane >= s) { a += ta; b += tb; }
        }
        if (lane < 8) { w1[lane] = a; w2[lane] = b; }
    }
    __syncthreads();
    int p1 = (wv > 0) ? w1[wv - 1] : 0, p2 = (wv > 0) ? w2[wv - 1] : 0;
    x1 += p1; x2 += p2;
    if (t < NB) { eoff[t] = x1 - v; boff[t] = x2 - (v + nib); ecur[t] = 0; }
    if (t == NB - 1) { eoff[NB] = x1; boff[NB] = x2; off[NNODES] = x2; }
    if (t >= 448) {  // fused atilde
        int idx = t - 448;
        int k = idx & 31;
        const float* a = (idx < 32) ? as5 : ad5;
        float s = 0.f;
        for (int f = 0; f < 128; ++f) s += W5[k * 128 + f] * a[f];
        atl[idx] = s;
    }
}

// block-aggregated scatter: per-block LDS hist -> one range-reservation atomic
// per (bucket, block) -> ticketed placement into contiguous runs.
__global__ __launch_bounds__(256) void bucket_scatter(const int* __restrict__ src,
                                                      const int* __restrict__ dst,
                                                      const int* __restrict__ eoff,
                                                      int* __restrict__ ecur,
                                                      uint* __restrict__ ebuf) {
    __shared__ int lh[NB];    // local hist -> global base
    __shared__ int lcur[NB];  // local ticket
    const int CH = (NEDGES + SCG - 1) / SCG;
    int c0 = blockIdx.x * CH;
    int c1 = min(c0 + CH, NEDGES);
    int t = threadIdx.x;
    for (int i = t; i < NB; i += 256) { lh[i] = 0; lcur[i] = 0; }
    __syncthreads();
    for (int e = c0 + t; e < c1; e += 256) atomicAdd(&lh[dst[e] >> 7], 1);
    __syncthreads();
    for (int i = t; i < NB; i += 256) {
        int c = lh[i];
        lh[i] = c ? (eoff[i] + atomicAdd(&ecur[i], c)) : 0;
    }
    __syncthreads();
    for (int e = c0 + t; e < c1; e += 256) {
        int d = dst[e];
        int bk = d >> 7;
        int p = lh[bk] + atomicAdd(&lcur[bk], 1);
        ebuf[p] = ((uint)(d & 127) << 16) | (uint)src[e];
    }
}

__global__ __launch_bounds__(256) void bucket_place(const uint* __restrict__ ebuf,
                                                    const int* __restrict__ eoff,
                                                    const int* __restrict__ boff,
                                                    int* __restrict__ off,
                                                    int* __restrict__ ssorted) {
    __shared__ int cnt[NPB];  // counts, then exclusive offsets
    __shared__ int cur[NPB];
    __shared__ int wtot[2];
    int b = blockIdx.x;
    int nib = (b == NB - 1) ? (NNODES - (NB - 1) * NPB) : NPB;
    int t = threadIdx.x;
    for (int i = t; i < NPB; i += 256) { cnt[i] = 0; cur[i] = 0; }
    __syncthreads();
    int e0 = eoff[b], e1 = eoff[b + 1];
    for (int i = e0 + t; i < e1; i += 256) atomicAdd(&cnt[ebuf[i] >> 16], 1);
    __syncthreads();
    int lane = t & 63, wv = t >> 6;
    int deg = (t < nib) ? cnt[t] + 1 : 0;  // +1 self-loop for real nodes
    int x = deg;
#pragma unroll
    for (int s = 1; s < 64; s <<= 1) {
        int tv = __shfl_up(x, s);
        if (lane >= s) x += tv;
    }
    if (lane == 63 && wv < 2) wtot[wv] = x;
    __syncthreads();
    int excl = x - deg + ((wv == 1) ? wtot[0] : 0);
    if (t < nib) {
        int base = boff[b] + excl;
        off[b * NPB + t] = base;
        cnt[t] = excl;                          // reuse as local offset
        ssorted[base + deg - 1] = b * NPB + t;  // self-loop in last slot
    }
    __syncthreads();
    int bb = boff[b];
    for (int i = e0 + t; i < e1; i += 256) {
        uint v = ebuf[i];
        int ld = v >> 16;
        int pos = bb + cnt[ld] + atomicAdd(&cur[ld], 1);
        ssorted[pos] = (int)(v & 0xffffu);
    }
}

// ===== dense matmul: O = (AFF? X*sc+sh : X) @ W (+bias), fused attn scores =====
// 64 x BN block tile, thread tile 4 x TN (TN=BN/16), register double-buffered
// K-tiles. AH=4 (BN=64): each head's 32 cols live in 8 lanes -> xor 1,2,4
// reduce, direct store. AH=1 (F=32): 16-lane row reduce, direct store.
template <int BN, bool WF32, bool WBF, bool AFF, bool BIAS, int AH>
__global__ __launch_bounds__(256) void matmul_rt(const float* __restrict__ X,
                                                 const float* __restrict__ W,
                                                 const float* __restrict__ scale,
                                                 const float* __restrict__ shift,
                                                 const float* __restrict__ bias,
                                                 const float* __restrict__ av_s,
                                                 const float* __restrict__ av_d,
                                                 float* __restrict__ Of,
                                                 ushort* __restrict__ Obf,
                                                 float* __restrict__ es,
                                                 float* __restrict__ ed,
                                                 int N, int K, int F) {
    constexpr int TN = BN / 16;
    constexpr int NXL = 4;              // 64*16/256 loads per thread (sX)
    constexpr int NWL = 16 * BN / 256;  // sW loads per thread
    __shared__ float sX[16][64 + 4];
    __shared__ float sW[16][BN + 4];
    int tid = threadIdx.x;
    int rowBase = blockIdx.x * 64, colBase = blockIdx.y * BN;
    int tr = (tid >> 4) * 4, tc = (tid & 15) * TN;
    float acc[4][TN];
#pragma unroll
    for (int x = 0; x < 4; ++x)
#pragma unroll
        for (int y = 0; y < TN; ++y) acc[x][y] = 0.f;

    float rx[NXL], rw[NWL];
    auto loadX = [&](int k0) {
#pragma unroll
        for (int j = 0; j < NXL; ++j) {
            int i = tid + j * 256;
            int r = i >> 4, k = i & 15;
            int gr = rowBase + r;
            float v = 0.f;
            if (gr < N) {
                v = X[(size_t)gr * K + k0 + k];
                if constexpr (AFF) v = fmaf(v, scale[k0 + k], shift[k0 + k]);
            }
            rx[j] = v;
        }
    };
    auto loadW = [&](int k0) {
#pragma unroll
        for (int j = 0; j < NWL; ++j) {
            int i = tid + j * 256;
            rw[j] = W[(size_t)(k0 + i / BN) * F + colBase + i % BN];
        }
    };

    loadX(0);
    loadW(0);
    const int T = K / 16;
    for (int t = 0; t < T; ++t) {
#pragma unroll
        for (int j = 0; j < NXL; ++j) {
            int i = tid + j * 256;
            sX[i & 15][i >> 4] = rx[j];
        }
#pragma unroll
        for (int j = 0; j < NWL; ++j) {
            int i = tid + j * 256;
            sW[i / BN][i % BN] = rw[j];
        }
        __syncthreads();
        if (t + 1 < T) {  // issue next tile's loads; they fly during compute
            loadX((t + 1) * 16);
            loadW((t + 1) * 16);
        }
#pragma unroll
        for (int k = 0; k < 16; ++k) {
            float4 av = *(const float4*)&sX[k][tr];
            float a[4] = {av.x, av.y, av.z, av.w};
            float b[TN];
            if constexpr (TN == 4) {
                float4 bv = *(const float4*)&sW[k][tc];
                b[0] = bv.x; b[1] = bv.y; b[2] = bv.z; b[3] = bv.w;
            } else {
                float2 bv = *(const float2*)&sW[k][tc];
                b[0] = bv.x; b[1] = bv.y;
            }
#pragma unroll
            for (int x = 0; x < 4; ++x)
#pragma unroll
                for (int y = 0; y < TN; ++y) acc[x][y] += a[x] * b[y];
        }
        __syncthreads();
    }

    float asv[TN], adv[TN];
    if constexpr (AH > 0) {
#pragma unroll
        for (int y = 0; y < TN; ++y) {
            asv[y] = av_s[colBase + tc + y];
            adv[y] = av_d[colBase + tc + y];
        }
    }

#pragma unroll
    for (int x = 0; x < 4; ++x) {
        int gr = rowBase + tr + x;
        float o[TN];
#pragma unroll
        for (int y = 0; y < TN; ++y) {
            o[y] = acc[x][y];
            if constexpr (BIAS) o[y] += bias[colBase + tc + y];
        }
        if (gr < N) {
            if constexpr (WF32) {
#pragma unroll
                for (int y = 0; y < TN; ++y) Of[(size_t)gr * F + colBase + tc + y] = o[y];
            }
            if constexpr (WBF) {
#pragma unroll
                for (int y = 0; y < TN; y += 2) {
                    uint pk = (uint)f2bf(o[y]) | ((uint)f2bf(o[y + 1]) << 16);
                    *(uint*)(Obf + (size_t)gr * F + colBase + tc + y) = pk;
                }
            }
        }
        if constexpr (AH > 0) {
            float ps = 0.f, pd = 0.f;
#pragma unroll
            for (int y = 0; y < TN; ++y) { ps += o[y] * asv[y]; pd += o[y] * adv[y]; }
            if constexpr (AH == 4) {
                // TN==4: thread's 4 cols in one 32-col head; 8 lanes cover it.
#pragma unroll
                for (int s = 1; s < 8; s <<= 1) { ps += __shfl_xor(ps, s); pd += __shfl_xor(pd, s); }
                if ((tid & 7) == 0 && gr < N) {
                    int hd = (colBase >> 5) + (tc >> 5);
                    es[(size_t)gr * 4 + hd] = ps;
                    ed[(size_t)gr * 4 + hd] = pd;
                }
            } else {
                // 16 lanes share the row, single head, single col-block
#pragma unroll
                for (int s = 1; s < 16; s <<= 1) { ps += __shfl_xor(ps, s); pd += __shfl_xor(pd, s); }
                if ((tid & 15) == 0 && gr < N) { es[gr] = ps; ed[gr] = pd; }
            }
        }
    }
}

// ====== gather softmax-aggregate, F=128, h in bf16 (one wave per dst node) ======
template <int HH>
__global__ __launch_bounds__(256) void node_agg_bf(const int* __restrict__ off,
                                                   const int* __restrict__ ssorted,
                                                   const ushort* __restrict__ Hb,
                                                   const float* __restrict__ es,
                                                   const float* __restrict__ ed,
                                                   const float* __restrict__ bias,
                                                   float* __restrict__ outp, int relu) {
    __shared__ float lds_ex[4][DEGC * HH];
    __shared__ int lds_s[4][DEGC];
    int wib = threadIdx.x >> 6;
    int lane = threadIdx.x & 63;
    int d = blockIdx.x * 4 + wib;
    int beg = off[d], end = off[d + 1];
    int m = end - beg;  // >= 1

    float edv[HH];
#pragma unroll
    for (int h = 0; h < HH; ++h) edv[h] = ed[(size_t)d * HH + h];
    float denp[HH];
#pragma unroll
    for (int h = 0; h < HH; ++h) denp[h] = 0.f;

    for (int base = 0; base < m; base += 64) {
        int i = base + lane;
        if (i < m) {
            int s = ssorted[beg + i];
            if (i < DEGC) lds_s[wib][i] = s;
            if constexpr (HH == 4) {
                float4 ev = ((const float4*)es)[s];
                float ea[4] = {ev.x, ev.y, ev.z, ev.w};
#pragma unroll
                for (int h = 0; h < 4; ++h) {
                    float a = ea[h] + edv[h];
                    a = a > 0.f ? a : 0.2f * a;
                    float ex = __expf(a);
                    denp[h] += ex;
                    if (i < DEGC) lds_ex[wib][i * 4 + h] = ex;
                }
            } else {
                float a = es[s] + edv[0];
                a = a > 0.f ? a : 0.2f * a;
                float ex = __expf(a);
                denp[0] += ex;
                if (i < DEGC) lds_ex[wib][i] = ex;
            }
        }
    }
#pragma unroll
    for (int h = 0; h < HH; ++h)
#pragma unroll
        for (int sft = 1; sft < 64; sft <<= 1) denp[h] += __shfl_xor(denp[h], sft);

    __syncthreads();

    const uint* Hu = (const uint*)Hb;
    int head;
    float den, edl;
    if constexpr (HH == 4) {
        head = lane >> 4;
        den = (lane < 32) ? ((lane < 16) ? denp[0] : denp[1])
                          : ((lane < 48) ? denp[2] : denp[3]);
        edl = (lane < 32) ? ((lane < 16) ? edv[0] : edv[1])
                          : ((lane < 48) ? edv[2] : edv[3]);
    } else {
        head = 0;
        den = denp[0];
        edl = edv[0];
    }
    float inv = 1.f / den;
    float acc0 = 0.f, acc1 = 0.f;
    int mu = m < DEGC ? m : DEGC;
    int i = 0;
    for (; i + 4 <= mu; i += 4) {  // 4-deep MLP
        int s0 = lds_s[wib][i], s1 = lds_s[wib][i + 1];
        int s2 = lds_s[wib][i + 2], s3 = lds_s[wib][i + 3];
        float w0 = lds_ex[wib][i * HH + head] * inv;
        float w1 = lds_ex[wib][(i + 1) * HH + head] * inv;
        float w2 = lds_ex[wib][(i + 2) * HH + head] * inv;
        float w3 = lds_ex[wib][(i + 3) * HH + head] * inv;
        uint v0 = Hu[(size_t)s0 * 64 + lane];
        uint v1 = Hu[(size_t)s1 * 64 + lane];
        uint v2 = Hu[(size_t)s2 * 64 + lane];
        uint v3 = Hu[(size_t)s3 * 64 + lane];
        float2 f0 = bf2f(v0), f1 = bf2f(v1), f2 = bf2f(v2), f3 = bf2f(v3);
        acc0 += w0 * f0.x + w1 * f1.x + w2 * f2.x + w3 * f3.x;
        acc1 += w0 * f0.y + w1 * f1.y + w2 * f2.y + w3 * f3.y;
    }
    for (; i < mu; ++i) {
        int s = lds_s[wib][i];
        float w = lds_ex[wib][i * HH + head] * inv;
        float2 f = bf2f(Hu[(size_t)s * 64 + lane]);
        acc0 += w * f.x;
        acc1 += w * f.y;
    }
    for (; i < m; ++i) {  // rare high-degree fallback
        int s = ssorted[beg + i];
        float a = es[(size_t)s * HH + head] + edl;
        a = a > 0.f ? a : 0.2f * a;
        float w = __expf(a) * inv;
        float2 f = bf2f(Hu[(size_t)s * 64 + lane]);
        acc0 += w * f.x;
        acc1 += w * f.y;
    }
    float v0 = acc0 + bias[2 * lane];
    float v1 = acc1 + bias[2 * lane + 1];
    if (relu) { v0 = fmaxf(v0, 0.f); v1 = fmaxf(v1, 0.f); }
    *(float2*)(outp + (size_t)d * 128 + 2 * lane) = make_float2(v0, v1);
}

// ====== gather softmax-aggregate, F=32, HH=1, h in fp32 ======
__global__ __launch_bounds__(256) void node_agg_f32(const int* __restrict__ off,
                                                    const int* __restrict__ ssorted,
                                                    const float* __restrict__ Hb,
                                                    const float* __restrict__ es,
                                                    const float* __restrict__ ed,
                                                    const float* __restrict__ bias,
                                                    float* __restrict__ outp, int relu) {
    __shared__ float lds_ex[4][DEGC];
    __shared__ int lds_s[4][DEGC];
    int wib = threadIdx.x >> 6;
    int lane = threadIdx.x & 63;
    int d = blockIdx.x * 4 + wib;
    int beg = off[d], end = off[d + 1];
    int m = end - beg;

    float edv = ed[d];
    float denp = 0.f;
    for (int base = 0; base < m; base += 64) {
        int i = base + lane;
        if (i < m) {
            int s = ssorted[beg + i];
            if (i < DEGC) lds_s[wib][i] = s;
            float a = es[s] + edv;
            a = a > 0.f ? a : 0.2f * a;
            float ex = __expf(a);
            denp += ex;
            if (i < DEGC) lds_ex[wib][i] = ex;
        }
    }
#pragma unroll
    for (int sft = 1; sft < 64; sft <<= 1) denp += __shfl_xor(denp, sft);

    __syncthreads();

    int sub = lane >> 5, f = lane & 31;
    float inv = 1.f / denp;
    float acc = 0.f;
    int mu = m < DEGC ? m : DEGC;
    int i = sub;
    for (; i + 2 < mu; i += 4) {  // 2-deep MLP per sub-wave
        int s0 = lds_s[wib][i], s1 = lds_s[wib][i + 2];
        float w0 = lds_ex[wib][i] * inv, w1 = lds_ex[wib][i + 2] * inv;
        float h0 = Hb[(size_t)s0 * 32 + f], h1 = Hb[(size_t)s1 * 32 + f];
        acc += w0 * h0 + w1 * h1;
    }
    for (; i < mu; i += 2) {
        int s = lds_s[wib][i];
        acc += lds_ex[wib][i] * inv * Hb[(size_t)s * 32 + f];
    }
    for (; i < m; i += 2) {
        int s = ssorted[beg + i];
        float a = es[s] + edv;
        a = a > 0.f ? a : 0.2f * a;
        acc += __expf(a) * inv * Hb[(size_t)s * 32 + f];
    }
    acc += __shfl_xor(acc, 32);
    if (sub == 0) {
        float v = acc + bias[f];
        if (relu) v = fmaxf(v, 0.f);
        outp[(size_t)d * 32 + f] = v;
    }
}

// ======= batchnorm stats; FINAL: last block also computes scale/shift =======
template <int F, bool FINAL>
__global__ __launch_bounds__(256) void bn_stats(const float* __restrict__ x,
                                                float* __restrict__ sums, int n,
                                                const float* __restrict__ g,
                                                const float* __restrict__ be,
                                                float* __restrict__ sc,
                                                float* __restrict__ sh,
                                                int* __restrict__ ctr, float inv_n) {
    constexpr int TPR = F / 4;
    constexpr int RPB = 256 / TPR;
    __shared__ float ls[2 * F];
    __shared__ int lastFlag;
    if (threadIdx.x < 2 * F) ls[threadIdx.x] = 0.f;
    int tf = threadIdx.x % TPR;
    int tr = threadIdx.x / TPR;
    float4 s = make_float4(0.f, 0.f, 0.f, 0.f), q = make_float4(0.f, 0.f, 0.f, 0.f);
    for (int r = blockIdx.x * RPB + tr; r < n; r += gridDim.x * RPB) {
        float4 v = *(const float4*)(x + (size_t)r * F + tf * 4);
        s.x += v.x; s.y += v.y; s.z += v.z; s.w += v.w;
        q.x += v.x * v.x; q.y += v.y * v.y; q.z += v.z * v.z; q.w += v.w * v.w;
    }
    __syncthreads();
    atomicAdd(&ls[tf * 4 + 0], s.x);
    atomicAdd(&ls[tf * 4 + 1], s.y);
    atomicAdd(&ls[tf * 4 + 2], s.z);
    atomicAdd(&ls[tf * 4 + 3], s.w);
    atomicAdd(&ls[F + tf * 4 + 0], q.x);
    atomicAdd(&ls[F + tf * 4 + 1], q.y);
    atomicAdd(&ls[F + tf * 4 + 2], q.z);
    atomicAdd(&ls[F + tf * 4 + 3], q.w);
    __syncthreads();
    if (threadIdx.x < 2 * F) atomicAdd(&sums[threadIdx.x], ls[threadIdx.x]);
    if constexpr (FINAL) {
        __threadfence();
        __syncthreads();  // all this block's global atomics drained (vmcnt)
        if (threadIdx.x == 0) {
            int old = atomicAdd(ctr, 1);
            lastFlag = (old == (int)gridDim.x - 1);
        }
        __syncthreads();
        if (lastFlag && threadIdx.x < F) {
            int f = threadIdx.x;
            float s1 = atomicAdd(&sums[f], 0.f);       // coherent read
            float s2 = atomicAdd(&sums[F + f], 0.f);
            float mu = s1 * inv_n;
            float var = s2 * inv_n - mu * mu;
            float sf = g[f] * rsqrtf(var + BN_EPS);
            sc[f] = sf;
            sh[f] = fmaf(-mu, sf, be[f]);
        }
    }
}

// bn + relu + fused GAT5 attn scores (one 32-lane group per row)
__global__ __launch_bounds__(256) void bn_relu_attn(const float* __restrict__ y,
                                                    const float* __restrict__ sums,
                                                    const float* __restrict__ g,
                                                    const float* __restrict__ be,
                                                    const float* __restrict__ atl,
                                                    float* __restrict__ o,
                                                    float* __restrict__ es,
                                                    float* __restrict__ ed) {
    int r = blockIdx.x * 8 + (threadIdx.x >> 5);
    int f = threadIdx.x & 31;
    float mu = sums[f] / (float)NNODES;
    float var = sums[32 + f] / (float)NNODES - mu * mu;
    float v = (y[(size_t)r * 32 + f] - mu) * rsqrtf(var + BN_EPS) * g[f] + be[f];
    v = fmaxf(v, 0.f);
    o[(size_t)r * 32 + f] = v;
    float ps = v * atl[f], pd = v * atl[32 + f];
#pragma unroll
    for (int s = 1; s < 32; s <<= 1) { ps += __shfl_xor(ps, s); pd += __shfl_xor(pd, s); }
    if (f == 0) { es[r] = ps; ed[r] = pd; }
}

extern "C" void kernel_launch(void* const* d_in, const int* in_sizes, int n_in, void* d_out,
                              int out_size, void* d_ws, size_t ws_size, hipStream_t stream) {
    const int N = NNODES, E = NEDGES;
    const float* x = (const float*)d_in[0];
    const int* ei = (const int*)d_in[1];
    const int* src = ei;
    const int* dst = ei + E;
    const float* W1 = (const float*)d_in[2];
    const float* as1 = (const float*)d_in[3];
    const float* ad1 = (const float*)d_in[4];
    const float* b1 = (const float*)d_in[5];
    const float* g1 = (const float*)d_in[6];
    const float* be1 = (const float*)d_in[7];
    const float* W2 = (const float*)d_in[8];
    const float* as2 = (const float*)d_in[9];
    const float* ad2 = (const float*)d_in[10];
    const float* b2 = (const float*)d_in[11];
    const float* g2 = (const float*)d_in[12];
    const float* be2 = (const float*)d_in[13];
    const float* W3 = (const float*)d_in[14];
    const float* as3 = (const float*)d_in[15];
    const float* ad3 = (const float*)d_in[16];
    const float* b3 = (const float*)d_in[17];
    const float* W4 = (const float*)d_in[18];
    const float* as4 = (const float*)d_in[19];
    const float* ad4 = (const float*)d_in[20];
    const float* b4 = (const float*)d_in[21];
    const float* g4 = (const float*)d_in[22];
    const float* be4 = (const float*)d_in[23];
    const float* W5 = (const float*)d_in[24];
    const float* as5 = (const float*)d_in[25];
    const float* ad5 = (const float*)d_in[26];
    const float* b5 = (const float*)d_in[27];
    float* out = (float*)d_out;

    // workspace layout (float-sized slots)
    float* ws = (float*)d_ws;
    float* bufAf = ws;                                      // N*128 fp32 (h for f32 layers)
    float* bufB = ws + (size_t)N * 128;                     // N*128 fp32 (activations)
    ushort* bufAbf = (ushort*)(ws + (size_t)2 * N * 128);   // N*128 bf16 (= N*64 floats)
    uint* ebuf = (uint*)bufAbf;                             // E uints, aliased (CSR build only)
    float* esA = ws + (size_t)2 * N * 128 + (size_t)N * 64; // N*4
    float* edA = esA + (size_t)N * 4;                       // N*4
    float* esB = edA + (size_t)N * 4;                       // N*4
    float* edB = esB + (size_t)N * 4;                       // N*4
    float* sums = edB + (size_t)N * 4;                      // 3*256
    float* zero32 = sums + 768;                             // 32
    int* bcnt = (int*)(zero32 + 32);                        // NB
    int* ctr = bcnt + NB;                                   // 2 (bn last-block counters)
    int* eoff = ctr + 2;                                    // NB+1
    int* boff = eoff + NB + 1;                              // NB+1
    int* ecur = boff + NB + 1;                              // NB
    float* sc1 = (float*)(ecur + NB);                       // 128
    float* sh1 = sc1 + 128;
    float* sc2 = sh1 + 128;
    float* sh2 = sc2 + 128;
    float* atl = sh2 + 128;                                 // 64 (ãs | ãd)
    int* off = (int*)(atl + 64);                            // N+1
    int* ssorted = off + N + 1;                             // E+N

    const int TB = 256;
    const int gAgg = N / 4;
    const dim3 mmG128((N + 63) / 64, 2);   // BN=64, two col-blocks
    const dim3 mmG32((N + 63) / 64, 1);    // BN=32, F=32
    const float inv_n = 1.f / (float)N;

    // zero sums(768) + zero32(32) + bcnt(NB) + ctr(2) in one contiguous shot
    hipMemsetAsync(sums, 0, (768 + 32 + NB + 2) * sizeof(float), stream);

    // ---- CSR-by-dst build (2-level bucket sort, block-aggregated scatter) ----
    bucket_hist<<<64, TB, 0, stream>>>(dst, bcnt);
    bucket_scan<<<1, 512, 0, stream>>>(bcnt, eoff, boff, ecur, off, W5, as5, ad5, atl);
    bucket_scatter<<<SCG, TB, 0, stream>>>(src, dst, eoff, ecur, ebuf);
    bucket_place<<<NB, TB, 0, stream>>>(ebuf, eoff, boff, off, ssorted);

    // ================= GAT1: 128 -> 4x32, relu, bn(fused fwd) =================
    matmul_rt<64, false, true, false, false, 4><<<mmG128, TB, 0, stream>>>(
        x, W1, nullptr, nullptr, nullptr, as1, ad1, nullptr, bufAbf, esA, edA, N, 128, 128);
    node_agg_bf<4><<<gAgg, TB, 0, stream>>>(off, ssorted, bufAbf, esA, edA, b1, bufB, 1);
    bn_stats<128, true><<<625, TB, 0, stream>>>(bufB, sums, N, g1, be1, sc1, sh1, ctr, inv_n);

    // ================= GAT2: 128 -> 4x32, relu, bn(fused fwd) =================
    matmul_rt<64, false, true, true, false, 4><<<mmG128, TB, 0, stream>>>(
        bufB, W2, sc1, sh1, nullptr, as2, ad2, nullptr, bufAbf, esB, edB, N, 128, 128);
    node_agg_bf<4><<<gAgg, TB, 0, stream>>>(off, ssorted, bufAbf, esB, edB, b2, bufB, 1);
    bn_stats<128, true><<<625, TB, 0, stream>>>(bufB, sums + 256, N, g2, be2, sc2, sh2,
                                                ctr + 1, inv_n);

    // ================= GAT3: 128 -> 32, relu (fp32 path, bn2 fused in) =================
    matmul_rt<32, true, false, true, false, 1><<<mmG32, TB, 0, stream>>>(
        bufB, W3, sc2, sh2, nullptr, as3, ad3, bufAf, nullptr, esA, edA, N, 128, 32);
    node_agg_f32<<<gAgg, TB, 0, stream>>>(off, ssorted, bufAf, esA, edA, b3, bufB, 1);

    // ================= GAT4: 32 -> 32, relu, bn, relu =================
    matmul_rt<32, true, false, false, false, 1><<<mmG32, TB, 0, stream>>>(
        bufB, W4, nullptr, nullptr, nullptr, as4, ad4, bufAf, nullptr, esA, edA, N, 32, 32);
    node_agg_f32<<<gAgg, TB, 0, stream>>>(off, ssorted, bufAf, esA, edA, b4, bufB, 1);
    bn_stats<32, false><<<625, TB, 0, stream>>>(bufB, sums + 512, N, nullptr, nullptr,
                                                nullptr, nullptr, nullptr, inv_n);
    bn_relu_attn<<<N / 8, TB, 0, stream>>>(bufB, sums + 512, g4, be4, atl, bufAf, esA, edA);

    // ================= GAT5: 32 -> 128 in r-space (exact fp32) =================
    node_agg_f32<<<gAgg, TB, 0, stream>>>(off, ssorted, bufAf, esA, edA, zero32, bufB, 0);
    matmul_rt<64, true, false, false, true, 0><<<mmG128, TB, 0, stream>>>(
        bufB, W5, nullptr, nullptr, b5, nullptr, nullptr, out, nullptr, nullptr, nullptr,
        N, 32, 128);
}

// Round 13
// 534.011 us; speedup vs baseline: 1.2639x; 1.0852x over previous
//
#include <hip/hip_runtime.h>
#include <math.h>

#define NNODES 50000
#define NEDGES 800000
#define BN_EPS 1e-5f
#define DEGC 128   // LDS-cached in-edges per node; fallback path beyond
#define NB 391     // buckets (128 nodes each; last has 80)
#define NPB 128
#define SCG 128    // scatter blocks (chunked)

typedef unsigned int uint;
typedef unsigned short ushort;

// fp32 -> bf16 (RNE)
static __device__ __forceinline__ ushort f2bf(float f) {
    uint u = __float_as_uint(f);
    return (ushort)((u + 0x7fffu + ((u >> 16) & 1u)) >> 16);
}
// 2 packed bf16 -> 2 fp32 (elem0 = low 16 bits)
static __device__ __forceinline__ float2 bf2f(uint v) {
    float2 r;
    r.x = __uint_as_float(v << 16);
    r.y = __uint_as_float(v & 0xffff0000u);
    return r;
}

// ================= CSR build via 2-level bucket sort =================
__global__ __launch_bounds__(256) void bucket_hist(const int* __restrict__ dst,
                                                   int* __restrict__ bcnt) {
    __shared__ int h[NB];
    for (int i = threadIdx.x; i < NB; i += 256) h[i] = 0;
    __syncthreads();
    for (int e = blockIdx.x * 256 + threadIdx.x; e < NEDGES; e += gridDim.x * 256)
        atomicAdd(&h[dst[e] >> 7], 1);
    __syncthreads();
    for (int i = threadIdx.x; i < NB; i += 256)
        if (h[i]) atomicAdd(&bcnt[i], h[i]);
}

// scan over buckets (+ fused atilde: atl[0..31]=W5@as5, atl[32..63]=W5@ad5
// computed by otherwise-idle threads 448..511)
__global__ void bucket_scan(const int* __restrict__ bcnt, int* __restrict__ eoff,
                            int* __restrict__ boff, int* __restrict__ ecur,
                            int* __restrict__ off, const float* __restrict__ W5,
                            const float* __restrict__ as5, const float* __restrict__ ad5,
                            float* __restrict__ atl) {
    __shared__ int w1[8], w2[8];
    int t = threadIdx.x, lane = t & 63, wv = t >> 6;  // 512 threads, 8 waves
    int v = (t < NB) ? bcnt[t] : 0;
    int nib = 0;
    if (t < NB) nib = (t == NB - 1) ? (NNODES - (NB - 1) * NPB) : NPB;
    int x1 = v, x2 = v + nib;
#pragma unroll
    for (int s = 1; s < 64; s <<= 1) {
        int t1 = __shfl_up(x1, s), t2 = __shfl_up(x2, s);
        if (lane >= s) { x1 += t1; x2 += t2; }
    }
    if (lane == 63) { w1[wv] = x1; w2[wv] = x2; }
    __syncthreads();
    if (wv == 0) {
        int a = (lane < 8) ? w1[lane] : 0, b = (lane < 8) ? w2[lane] : 0;
#pragma unroll
        for (int s = 1; s < 8; s <<= 1) {
            int ta = __shfl_up(a, s), tb = __shfl_up(b, s);
            if (lane >= s) { a += ta; b += tb; }
        }
        if (lane < 8) { w1[lane] = a; w2[lane] = b; }
    }
    __syncthreads();
    int p1 = (wv > 0) ? w1[wv - 1] : 0, p2 = (wv > 0) ? w2[wv - 1] : 0;
    x1 += p1; x2 += p2;
    if (t < NB) { eoff[t] = x1 - v; boff[t] = x2 - (v + nib); ecur[t] = 0; }
    if (t == NB - 1) { eoff[NB] = x1; boff[NB] = x2; off[NNODES] = x2; }
    if (t >= 448) {  // fused atilde
        int idx = t - 448;
        int k = idx & 31;
        const float* a = (idx < 32) ? as5 : ad5;
        float s = 0.f;
        for (int f = 0; f < 128; ++f) s += W5[k * 128 + f] * a[f];
        atl[idx] = s;
    }
}

// block-aggregated scatter: per-block LDS hist -> one range-reservation atomic
// per (bucket, block) -> ticketed placement into contiguous runs.
__global__ __launch_bounds__(256) void bucket_scatter(const int* __restrict__ src,
                                                      const int* __restrict__ dst,
                                                      const int* __restrict__ eoff,
                                                      int* __restrict__ ecur,
                                                      uint* __restrict__ ebuf) {
    __shared__ int lh[NB];    // local hist -> global base
    __shared__ int lcur[NB];  // local ticket
    const int CH = (NEDGES + SCG - 1) / SCG;
    int c0 = blockIdx.x * CH;
    int c1 = min(c0 + CH, NEDGES);
    int t = threadIdx.x;
    for (int i = t; i < NB; i += 256) { lh[i] = 0; lcur[i] = 0; }
    __syncthreads();
    for (int e = c0 + t; e < c1; e += 256) atomicAdd(&lh[dst[e] >> 7], 1);
    __syncthreads();
    for (int i = t; i < NB; i += 256) {
        int c = lh[i];
        lh[i] = c ? (eoff[i] + atomicAdd(&ecur[i], c)) : 0;
    }
    __syncthreads();
    for (int e = c0 + t; e < c1; e += 256) {
        int d = dst[e];
        int bk = d >> 7;
        int p = lh[bk] + atomicAdd(&lcur[bk], 1);
        ebuf[p] = ((uint)(d & 127) << 16) | (uint)src[e];
    }
}

__global__ __launch_bounds__(256) void bucket_place(const uint* __restrict__ ebuf,
                                                    const int* __restrict__ eoff,
                                                    const int* __restrict__ boff,
                                                    int* __restrict__ off,
                                                    int* __restrict__ ssorted) {
    __shared__ int cnt[NPB];  // counts, then exclusive offsets
    __shared__ int cur[NPB];
    __shared__ int wtot[2];
    int b = blockIdx.x;
    int nib = (b == NB - 1) ? (NNODES - (NB - 1) * NPB) : NPB;
    int t = threadIdx.x;
    for (int i = t; i < NPB; i += 256) { cnt[i] = 0; cur[i] = 0; }
    __syncthreads();
    int e0 = eoff[b], e1 = eoff[b + 1];
    for (int i = e0 + t; i < e1; i += 256) atomicAdd(&cnt[ebuf[i] >> 16], 1);
    __syncthreads();
    int lane = t & 63, wv = t >> 6;
    int deg = (t < nib) ? cnt[t] + 1 : 0;  // +1 self-loop for real nodes
    int x = deg;
#pragma unroll
    for (int s = 1; s < 64; s <<= 1) {
        int tv = __shfl_up(x, s);
        if (lane >= s) x += tv;
    }
    if (lane == 63 && wv < 2) wtot[wv] = x;
    __syncthreads();
    int excl = x - deg + ((wv == 1) ? wtot[0] : 0);
    if (t < nib) {
        int base = boff[b] + excl;
        off[b * NPB + t] = base;
        cnt[t] = excl;                          // reuse as local offset
        ssorted[base + deg - 1] = b * NPB + t;  // self-loop in last slot
    }
    __syncthreads();
    int bb = boff[b];
    for (int i = e0 + t; i < e1; i += 256) {
        uint v = ebuf[i];
        int ld = v >> 16;
        int pos = bb + cnt[ld] + atomicAdd(&cur[ld], 1);
        ssorted[pos] = (int)(v & 0xffffu);
    }
}

// ===== dense matmul: O = (AFF? bn(X) : X) @ W (+bias), fused attn scores =====
// 64 x BN block tile, thread tile 4 x TN (TN=BN/16), register double-buffered
// K-tiles. AFF: bn scale/shift computed in-block from raw sums (consumer-side
// finalization — no fence, dispatch boundary orders the atomics). AH=4
// (BN=64): head's 32 cols in 8 lanes -> xor 1,2,4 reduce, direct store.
// AH=1 (F=32): 16-lane row reduce, direct store.
template <int BN, bool WF32, bool WBF, bool AFF, bool BIAS, int AH>
__global__ __launch_bounds__(256) void matmul_rt(const float* __restrict__ X,
                                                 const float* __restrict__ W,
                                                 const float* __restrict__ bnsums,
                                                 const float* __restrict__ bng,
                                                 const float* __restrict__ bnbe,
                                                 const float* __restrict__ bias,
                                                 const float* __restrict__ av_s,
                                                 const float* __restrict__ av_d,
                                                 float* __restrict__ Of,
                                                 ushort* __restrict__ Obf,
                                                 float* __restrict__ es,
                                                 float* __restrict__ ed,
                                                 int N, int K, int F, float inv_n) {
    constexpr int TN = BN / 16;
    constexpr int NXL = 4;              // 64*16/256 loads per thread (sX)
    constexpr int NWL = 16 * BN / 256;  // sW loads per thread
    __shared__ float sX[16][64 + 4];
    __shared__ float sW[16][BN + 4];
    __shared__ float sSc[128], sSh[128];
    int tid = threadIdx.x;
    int rowBase = blockIdx.x * 64, colBase = blockIdx.y * BN;
    int tr = (tid >> 4) * 4, tc = (tid & 15) * TN;

    if constexpr (AFF) {  // consumer-side bn finalization (K <= 128)
        if (tid < K) {
            float mu = bnsums[tid] * inv_n;
            float var = bnsums[K + tid] * inv_n - mu * mu;
            float s = bng[tid] * rsqrtf(var + BN_EPS);
            sSc[tid] = s;
            sSh[tid] = fmaf(-mu, s, bnbe[tid]);
        }
        __syncthreads();
    }

    float acc[4][TN];
#pragma unroll
    for (int x = 0; x < 4; ++x)
#pragma unroll
        for (int y = 0; y < TN; ++y) acc[x][y] = 0.f;

    float rx[NXL], rw[NWL];
    auto loadX = [&](int k0) {
#pragma unroll
        for (int j = 0; j < NXL; ++j) {
            int i = tid + j * 256;
            int r = i >> 4, k = i & 15;
            int gr = rowBase + r;
            float v = 0.f;
            if (gr < N) {
                v = X[(size_t)gr * K + k0 + k];
                if constexpr (AFF) v = fmaf(v, sSc[k0 + k], sSh[k0 + k]);
            }
            rx[j] = v;
        }
    };
    auto loadW = [&](int k0) {
#pragma unroll
        for (int j = 0; j < NWL; ++j) {
            int i = tid + j * 256;
            rw[j] = W[(size_t)(k0 + i / BN) * F + colBase + i % BN];
        }
    };

    loadX(0);
    loadW(0);
    const int T = K / 16;
    for (int t = 0; t < T; ++t) {
#pragma unroll
        for (int j = 0; j < NXL; ++j) {
            int i = tid + j * 256;
            sX[i & 15][i >> 4] = rx[j];
        }
#pragma unroll
        for (int j = 0; j < NWL; ++j) {
            int i = tid + j * 256;
            sW[i / BN][i % BN] = rw[j];
        }
        __syncthreads();
        if (t + 1 < T) {  // issue next tile's loads; they fly during compute
            loadX((t + 1) * 16);
            loadW((t + 1) * 16);
        }
#pragma unroll
        for (int k = 0; k < 16; ++k) {
            float4 av = *(const float4*)&sX[k][tr];
            float a[4] = {av.x, av.y, av.z, av.w};
            float b[TN];
            if constexpr (TN == 4) {
                float4 bv = *(const float4*)&sW[k][tc];
                b[0] = bv.x; b[1] = bv.y; b[2] = bv.z; b[3] = bv.w;
            } else {
                float2 bv = *(const float2*)&sW[k][tc];
                b[0] = bv.x; b[1] = bv.y;
            }
#pragma unroll
            for (int x = 0; x < 4; ++x)
#pragma unroll
                for (int y = 0; y < TN; ++y) acc[x][y] += a[x] * b[y];
        }
        __syncthreads();
    }

    float asv[TN], adv[TN];
    if constexpr (AH > 0) {
#pragma unroll
        for (int y = 0; y < TN; ++y) {
            asv[y] = av_s[colBase + tc + y];
            adv[y] = av_d[colBase + tc + y];
        }
    }

#pragma unroll
    for (int x = 0; x < 4; ++x) {
        int gr = rowBase + tr + x;
        float o[TN];
#pragma unroll
        for (int y = 0; y < TN; ++y) {
            o[y] = acc[x][y];
            if constexpr (BIAS) o[y] += bias[colBase + tc + y];
        }
        if (gr < N) {
            if constexpr (WF32) {
#pragma unroll
                for (int y = 0; y < TN; ++y) Of[(size_t)gr * F + colBase + tc + y] = o[y];
            }
            if constexpr (WBF) {
#pragma unroll
                for (int y = 0; y < TN; y += 2) {
                    uint pk = (uint)f2bf(o[y]) | ((uint)f2bf(o[y + 1]) << 16);
                    *(uint*)(Obf + (size_t)gr * F + colBase + tc + y) = pk;
                }
            }
        }
        if constexpr (AH > 0) {
            float ps = 0.f, pd = 0.f;
#pragma unroll
            for (int y = 0; y < TN; ++y) { ps += o[y] * asv[y]; pd += o[y] * adv[y]; }
            if constexpr (AH == 4) {
                // TN==4: thread's 4 cols in one 32-col head; 8 lanes cover it.
#pragma unroll
                for (int s = 1; s < 8; s <<= 1) { ps += __shfl_xor(ps, s); pd += __shfl_xor(pd, s); }
                if ((tid & 7) == 0 && gr < N) {
                    int hd = (colBase >> 5) + (tc >> 5);
                    es[(size_t)gr * 4 + hd] = ps;
                    ed[(size_t)gr * 4 + hd] = pd;
                }
            } else {
                // 16 lanes share the row, single head, single col-block
#pragma unroll
                for (int s = 1; s < 16; s <<= 1) { ps += __shfl_xor(ps, s); pd += __shfl_xor(pd, s); }
                if ((tid & 15) == 0 && gr < N) { es[gr] = ps; ed[gr] = pd; }
            }
        }
    }
}

// ====== gather softmax-aggregate, F=128, h in bf16 (one wave per dst node) ======
template <int HH>
__global__ __launch_bounds__(256) void node_agg_bf(const int* __restrict__ off,
                                                   const int* __restrict__ ssorted,
                                                   const ushort* __restrict__ Hb,
                                                   const float* __restrict__ es,
                                                   const float* __restrict__ ed,
                                                   const float* __restrict__ bias,
                                                   float* __restrict__ outp, int relu) {
    __shared__ float lds_ex[4][DEGC * HH];
    __shared__ int lds_s[4][DEGC];
    int wib = threadIdx.x >> 6;
    int lane = threadIdx.x & 63;
    int d = blockIdx.x * 4 + wib;
    int beg = off[d], end = off[d + 1];
    int m = end - beg;  // >= 1

    float edv[HH];
#pragma unroll
    for (int h = 0; h < HH; ++h) edv[h] = ed[(size_t)d * HH + h];
    float denp[HH];
#pragma unroll
    for (int h = 0; h < HH; ++h) denp[h] = 0.f;

    for (int base = 0; base < m; base += 64) {
        int i = base + lane;
        if (i < m) {
            int s = ssorted[beg + i];
            if (i < DEGC) lds_s[wib][i] = s;
            if constexpr (HH == 4) {
                float4 ev = ((const float4*)es)[s];
                float ea[4] = {ev.x, ev.y, ev.z, ev.w};
#pragma unroll
                for (int h = 0; h < 4; ++h) {
                    float a = ea[h] + edv[h];
                    a = a > 0.f ? a : 0.2f * a;
                    float ex = __expf(a);
                    denp[h] += ex;
                    if (i < DEGC) lds_ex[wib][i * 4 + h] = ex;
                }
            } else {
                float a = es[s] + edv[0];
                a = a > 0.f ? a : 0.2f * a;
                float ex = __expf(a);
                denp[0] += ex;
                if (i < DEGC) lds_ex[wib][i] = ex;
            }
        }
    }
#pragma unroll
    for (int h = 0; h < HH; ++h)
#pragma unroll
        for (int sft = 1; sft < 64; sft <<= 1) denp[h] += __shfl_xor(denp[h], sft);

    __syncthreads();

    const uint* Hu = (const uint*)Hb;
    int head;
    float den, edl;
    if constexpr (HH == 4) {
        head = lane >> 4;
        den = (lane < 32) ? ((lane < 16) ? denp[0] : denp[1])
                          : ((lane < 48) ? denp[2] : denp[3]);
        edl = (lane < 32) ? ((lane < 16) ? edv[0] : edv[1])
                          : ((lane < 48) ? edv[2] : edv[3]);
    } else {
        head = 0;
        den = denp[0];
        edl = edv[0];
    }
    float inv = 1.f / den;
    float acc0 = 0.f, acc1 = 0.f;
    int mu = m < DEGC ? m : DEGC;
    int i = 0;
    for (; i + 4 <= mu; i += 4) {  // 4-deep MLP
        int s0 = lds_s[wib][i], s1 = lds_s[wib][i + 1];
        int s2 = lds_s[wib][i + 2], s3 = lds_s[wib][i + 3];
        float w0 = lds_ex[wib][i * HH + head] * inv;
        float w1 = lds_ex[wib][(i + 1) * HH + head] * inv;
        float w2 = lds_ex[wib][(i + 2) * HH + head] * inv;
        float w3 = lds_ex[wib][(i + 3) * HH + head] * inv;
        uint v0 = Hu[(size_t)s0 * 64 + lane];
        uint v1 = Hu[(size_t)s1 * 64 + lane];
        uint v2 = Hu[(size_t)s2 * 64 + lane];
        uint v3 = Hu[(size_t)s3 * 64 + lane];
        float2 f0 = bf2f(v0), f1 = bf2f(v1), f2 = bf2f(v2), f3 = bf2f(v3);
        acc0 += w0 * f0.x + w1 * f1.x + w2 * f2.x + w3 * f3.x;
        acc1 += w0 * f0.y + w1 * f1.y + w2 * f2.y + w3 * f3.y;
    }
    for (; i < mu; ++i) {
        int s = lds_s[wib][i];
        float w = lds_ex[wib][i * HH + head] * inv;
        float2 f = bf2f(Hu[(size_t)s * 64 + lane]);
        acc0 += w * f.x;
        acc1 += w * f.y;
    }
    for (; i < m; ++i) {  // rare high-degree fallback
        int s = ssorted[beg + i];
        float a = es[(size_t)s * HH + head] + edl;
        a = a > 0.f ? a : 0.2f * a;
        float w = __expf(a) * inv;
        float2 f = bf2f(Hu[(size_t)s * 64 + lane]);
        acc0 += w * f.x;
        acc1 += w * f.y;
    }
    float v0 = acc0 + bias[2 * lane];
    float v1 = acc1 + bias[2 * lane + 1];
    if (relu) { v0 = fmaxf(v0, 0.f); v1 = fmaxf(v1, 0.f); }
    *(float2*)(outp + (size_t)d * 128 + 2 * lane) = make_float2(v0, v1);
}

// ====== gather softmax-aggregate, F=32, HH=1, h in fp32 ======
__global__ __launch_bounds__(256) void node_agg_f32(const int* __restrict__ off,
                                                    const int* __restrict__ ssorted,
                                                    const float* __restrict__ Hb,
                                                    const float* __restrict__ es,
                                                    const float* __restrict__ ed,
                                                    const float* __restrict__ bias,
                                                    float* __restrict__ outp, int relu) {
    __shared__ float lds_ex[4][DEGC];
    __shared__ int lds_s[4][DEGC];
    int wib = threadIdx.x >> 6;
    int lane = threadIdx.x & 63;
    int d = blockIdx.x * 4 + wib;
    int beg = off[d], end = off[d + 1];
    int m = end - beg;

    float edv = ed[d];
    float denp = 0.f;
    for (int base = 0; base < m; base += 64) {
        int i = base + lane;
        if (i < m) {
            int s = ssorted[beg + i];
            if (i < DEGC) lds_s[wib][i] = s;
            float a = es[s] + edv;
            a = a > 0.f ? a : 0.2f * a;
            float ex = __expf(a);
            denp += ex;
            if (i < DEGC) lds_ex[wib][i] = ex;
        }
    }
#pragma unroll
    for (int sft = 1; sft < 64; sft <<= 1) denp += __shfl_xor(denp, sft);

    __syncthreads();

    int sub = lane >> 5, f = lane & 31;
    float inv = 1.f / denp;
    float acc = 0.f;
    int mu = m < DEGC ? m : DEGC;
    int i = sub;
    for (; i + 2 < mu; i += 4) {  // 2-deep MLP per sub-wave
        int s0 = lds_s[wib][i], s1 = lds_s[wib][i + 2];
        float w0 = lds_ex[wib][i] * inv, w1 = lds_ex[wib][i + 2] * inv;
        float h0 = Hb[(size_t)s0 * 32 + f], h1 = Hb[(size_t)s1 * 32 + f];
        acc += w0 * h0 + w1 * h1;
    }
    for (; i < mu; i += 2) {
        int s = lds_s[wib][i];
        acc += lds_ex[wib][i] * inv * Hb[(size_t)s * 32 + f];
    }
    for (; i < m; i += 2) {
        int s = ssorted[beg + i];
        float a = es[s] + edv;
        a = a > 0.f ? a : 0.2f * a;
        acc += __expf(a) * inv * Hb[(size_t)s * 32 + f];
    }
    acc += __shfl_xor(acc, 32);
    if (sub == 0) {
        float v = acc + bias[f];
        if (relu) v = fmaxf(v, 0.f);
        outp[(size_t)d * 32 + f] = v;
    }
}

// ================= batchnorm stats (plain; finalization in consumer) =================
template <int F>
__global__ __launch_bounds__(256) void bn_stats(const float* __restrict__ x,
                                                float* __restrict__ sums, int n) {
    constexpr int TPR = F / 4;
    constexpr int RPB = 256 / TPR;
    __shared__ float ls[2 * F];
    if (threadIdx.x < 2 * F) ls[threadIdx.x] = 0.f;
    int tf = threadIdx.x % TPR;
    int tr = threadIdx.x / TPR;
    float4 s = make_float4(0.f, 0.f, 0.f, 0.f), q = make_float4(0.f, 0.f, 0.f, 0.f);
    for (int r = blockIdx.x * RPB + tr; r < n; r += gridDim.x * RPB) {
        float4 v = *(const float4*)(x + (size_t)r * F + tf * 4);
        s.x += v.x; s.y += v.y; s.z += v.z; s.w += v.w;
        q.x += v.x * v.x; q.y += v.y * v.y; q.z += v.z * v.z; q.w += v.w * v.w;
    }
    __syncthreads();
    atomicAdd(&ls[tf * 4 + 0], s.x);
    atomicAdd(&ls[tf * 4 + 1], s.y);
    atomicAdd(&ls[tf * 4 + 2], s.z);
    atomicAdd(&ls[tf * 4 + 3], s.w);
    atomicAdd(&ls[F + tf * 4 + 0], q.x);
    atomicAdd(&ls[F + tf * 4 + 1], q.y);
    atomicAdd(&ls[F + tf * 4 + 2], q.z);
    atomicAdd(&ls[F + tf * 4 + 3], q.w);
    __syncthreads();
    if (threadIdx.x < 2 * F) atomicAdd(&sums[threadIdx.x], ls[threadIdx.x]);
}

// bn + relu + fused GAT5 attn scores (one 32-lane group per row)
__global__ __launch_bounds__(256) void bn_relu_attn(const float* __restrict__ y,
                                                    const float* __restrict__ sums,
                                                    const float* __restrict__ g,
                                                    const float* __restrict__ be,
                                                    const float* __restrict__ atl,
                                                    float* __restrict__ o,
                                                    float* __restrict__ es,
                                                    float* __restrict__ ed) {
    int r = blockIdx.x * 8 + (threadIdx.x >> 5);
    int f = threadIdx.x & 31;
    float mu = sums[f] / (float)NNODES;
    float var = sums[32 + f] / (float)NNODES - mu * mu;
    float v = (y[(size_t)r * 32 + f] - mu) * rsqrtf(var + BN_EPS) * g[f] + be[f];
    v = fmaxf(v, 0.f);
    o[(size_t)r * 32 + f] = v;
    float ps = v * atl[f], pd = v * atl[32 + f];
#pragma unroll
    for (int s = 1; s < 32; s <<= 1) { ps += __shfl_xor(ps, s); pd += __shfl_xor(pd, s); }
    if (f == 0) { es[r] = ps; ed[r] = pd; }
}

extern "C" void kernel_launch(void* const* d_in, const int* in_sizes, int n_in, void* d_out,
                              int out_size, void* d_ws, size_t ws_size, hipStream_t stream) {
    const int N = NNODES, E = NEDGES;
    const float* x = (const float*)d_in[0];
    const int* ei = (const int*)d_in[1];
    const int* src = ei;
    const int* dst = ei + E;
    const float* W1 = (const float*)d_in[2];
    const float* as1 = (const float*)d_in[3];
    const float* ad1 = (const float*)d_in[4];
    const float* b1 = (const float*)d_in[5];
    const float* g1 = (const float*)d_in[6];
    const float* be1 = (const float*)d_in[7];
    const float* W2 = (const float*)d_in[8];
    const float* as2 = (const float*)d_in[9];
    const float* ad2 = (const float*)d_in[10];
    const float* b2 = (const float*)d_in[11];
    const float* g2 = (const float*)d_in[12];
    const float* be2 = (const float*)d_in[13];
    const float* W3 = (const float*)d_in[14];
    const float* as3 = (const float*)d_in[15];
    const float* ad3 = (const float*)d_in[16];
    const float* b3 = (const float*)d_in[17];
    const float* W4 = (const float*)d_in[18];
    const float* as4 = (const float*)d_in[19];
    const float* ad4 = (const float*)d_in[20];
    const float* b4 = (const float*)d_in[21];
    const float* g4 = (const float*)d_in[22];
    const float* be4 = (const float*)d_in[23];
    const float* W5 = (const float*)d_in[24];
    const float* as5 = (const float*)d_in[25];
    const float* ad5 = (const float*)d_in[26];
    const float* b5 = (const float*)d_in[27];
    float* out = (float*)d_out;

    // workspace layout (float-sized slots)
    float* ws = (float*)d_ws;
    float* bufAf = ws;                                      // N*128 fp32 (h for f32 layers)
    float* bufB = ws + (size_t)N * 128;                     // N*128 fp32 (activations)
    ushort* bufAbf = (ushort*)(ws + (size_t)2 * N * 128);   // N*128 bf16 (= N*64 floats)
    uint* ebuf = (uint*)bufAbf;                             // E uints, aliased (CSR build only)
    float* esA = ws + (size_t)2 * N * 128 + (size_t)N * 64; // N*4
    float* edA = esA + (size_t)N * 4;                       // N*4
    float* esB = edA + (size_t)N * 4;                       // N*4
    float* edB = esB + (size_t)N * 4;                       // N*4
    float* sums = edB + (size_t)N * 4;                      // 3*256
    float* zero32 = sums + 768;                             // 32
    int* bcnt = (int*)(zero32 + 32);                        // NB
    int* eoff = bcnt + NB;                                  // NB+1
    int* boff = eoff + NB + 1;                              // NB+1
    int* ecur = boff + NB + 1;                              // NB
    float* atl = (float*)(ecur + NB);                       // 64 (ãs | ãd)
    int* off = (int*)(atl + 64);                            // N+1
    int* ssorted = off + N + 1;                             // E+N

    const int TB = 256;
    const int gAgg = N / 4;
    const dim3 mmG128((N + 63) / 64, 2);   // BN=64, two col-blocks
    const dim3 mmG32((N + 63) / 64, 1);    // BN=32, F=32
    const float inv_n = 1.f / (float)N;

    // zero sums(768) + zero32(32) + bcnt(NB) in one contiguous shot
    hipMemsetAsync(sums, 0, (768 + 32 + NB) * sizeof(float), stream);

    // ---- CSR-by-dst build (2-level bucket sort, block-aggregated scatter) ----
    bucket_hist<<<64, TB, 0, stream>>>(dst, bcnt);
    bucket_scan<<<1, 512, 0, stream>>>(bcnt, eoff, boff, ecur, off, W5, as5, ad5, atl);
    bucket_scatter<<<SCG, TB, 0, stream>>>(src, dst, eoff, ecur, ebuf);
    bucket_place<<<NB, TB, 0, stream>>>(ebuf, eoff, boff, off, ssorted);

    // ================= GAT1: 128 -> 4x32, relu, bn(stats; finalized by GAT2 mm) =====
    matmul_rt<64, false, true, false, false, 4><<<mmG128, TB, 0, stream>>>(
        x, W1, nullptr, nullptr, nullptr, nullptr, as1, ad1, nullptr, bufAbf, esA, edA,
        N, 128, 128, inv_n);
    node_agg_bf<4><<<gAgg, TB, 0, stream>>>(off, ssorted, bufAbf, esA, edA, b1, bufB, 1);
    bn_stats<128><<<625, TB, 0, stream>>>(bufB, sums, N);

    // ================= GAT2: 128 -> 4x32, relu, bn(stats; finalized by GAT3 mm) =====
    matmul_rt<64, false, true, true, false, 4><<<mmG128, TB, 0, stream>>>(
        bufB, W2, sums, g1, be1, nullptr, as2, ad2, nullptr, bufAbf, esB, edB,
        N, 128, 128, inv_n);
    node_agg_bf<4><<<gAgg, TB, 0, stream>>>(off, ssorted, bufAbf, esB, edB, b2, bufB, 1);
    bn_stats<128><<<625, TB, 0, stream>>>(bufB, sums + 256, N);

    // ================= GAT3: 128 -> 32, relu (fp32 path, bn2 consumer-fused) =========
    matmul_rt<32, true, false, true, false, 1><<<mmG32, TB, 0, stream>>>(
        bufB, W3, sums + 256, g2, be2, nullptr, as3, ad3, bufAf, nullptr, esA, edA,
        N, 128, 32, inv_n);
    node_agg_f32<<<gAgg, TB, 0, stream>>>(off, ssorted, bufAf, esA, edA, b3, bufB, 1);

    // ================= GAT4: 32 -> 32, relu, bn, relu =================
    matmul_rt<32, true, false, false, false, 1><<<mmG32, TB, 0, stream>>>(
        bufB, W4, nullptr, nullptr, nullptr, nullptr, as4, ad4, bufAf, nullptr, esA, edA,
        N, 32, 32, inv_n);
    node_agg_f32<<<gAgg, TB, 0, stream>>>(off, ssorted, bufAf, esA, edA, b4, bufB, 1);
    bn_stats<32><<<625, TB, 0, stream>>>(bufB, sums + 512, N);
    bn_relu_attn<<<N / 8, TB, 0, stream>>>(bufB, sums + 512, g4, be4, atl, bufAf, esA, edA);

    // ================= GAT5: 32 -> 128 in r-space (exact fp32) =================
    node_agg_f32<<<gAgg, TB, 0, stream>>>(off, ssorted, bufAf, esA, edA, zero32, bufB, 0);
    matmul_rt<64, true, false, false, true, 0><<<mmG128, TB, 0, stream>>>(
        bufB, W5, nullptr, nullptr, nullptr, b5, nullptr, nullptr, out, nullptr, nullptr,
        nullptr, N, 32, 128, inv_n);
}